// Round 10
// baseline (194.026 us; speedup 1.0000x reference)
//
#include <hip/hip_runtime.h>
#include <stdint.h>

typedef unsigned short u16;
typedef __attribute__((ext_vector_type(8))) short bf16x8;   // 8 bf16 in 4 VGPRs
typedef __attribute__((ext_vector_type(4))) float floatx4;

#define MFMA16(a, b, c) __builtin_amdgcn_mfma_f32_16x16x32_bf16(a, b, c, 0, 0, 0)
#define MEMFENCE asm volatile("" ::: "memory")
#define WAIT_LGKM0 asm volatile("s_waitcnt lgkmcnt(0)" ::: "memory")

#if __has_builtin(__builtin_amdgcn_exp2f)
#define EXP2(x) __builtin_amdgcn_exp2f(x)
#else
#define EXP2(x) __expf(0.6931471805599453f * (x))
#endif

__device__ __forceinline__ u16 f2bf(float f) {   // round-to-nearest-even
  unsigned u = __builtin_bit_cast(unsigned, f);
  return (u16)((u + 0x7FFFu + ((u >> 16) & 1u)) >> 16);
}
__device__ __forceinline__ u16 f2bf_hu(float f) {  // round-half-up (cheaper)
  return (u16)((__builtin_bit_cast(unsigned, f) + 0x8000u) >> 16);
}
__device__ __forceinline__ float bf2f(u16 v) {
  return __builtin_bit_cast(float, (unsigned)v << 16);
}

// async global->LDS, 16B/lane. LDS dest = wave-uniform base + lane*16 (HW).
__device__ __forceinline__ void glds16(void* lds, const void* g) {
  __builtin_amdgcn_global_load_lds((const __attribute__((address_space(1))) void*)g,
                                   (__attribute__((address_space(3))) void*)lds,
                                   16, 0, 0);
}

// ---------------------------------------------------------------- convert
__global__ __launch_bounds__(256) void cvt_all(
    const float* __restrict__ x, const float* __restrict__ w0,
    const float* __restrict__ w1, const float* __restrict__ w2,
    u16* __restrict__ xb, u16* __restrict__ Wb) {
  const int bid = blockIdx.x;
  const float* src;
  u16* dst;
  int i;
  if (bid < 4096) {
    src = x; dst = xb; i = bid * 256 + threadIdx.x;
  } else {
    const int z = (bid - 4096) >> 10;
    src = (z == 0) ? w0 : (z == 1) ? w1 : w2;
    dst = Wb + (size_t)z * (1024 * 1024);
    i = ((bid - 4096) & 1023) * 256 + threadIdx.x;
  }
  float4 f = reinterpret_cast<const float4*>(src)[i];
  ushort4 o;
  o.x = f2bf(f.x); o.y = f2bf(f.y); o.z = f2bf(f.z); o.w = f2bf(f.w);
  reinterpret_cast<ushort4*>(dst)[i] = o;
}

// ---------------------------------------------------------------- QKV GEMM
// (unchanged from R8 — proven). 128x128 tile, BK=64, 768 blocks = 3/CU,
// XOR-swizzled LDS. which=0 -> Q (pre-scaled 0.25*log2e), 1 -> K, 2 -> V^T.
__global__ __launch_bounds__(256, 3) void qkv_gemm(
    const u16* __restrict__ xb, const u16* __restrict__ Wb,
    const float* __restrict__ bq, const float* __restrict__ bk,
    const float* __restrict__ bv,
    u16* __restrict__ Qb, u16* __restrict__ Kb, u16* __restrict__ VTb) {
  __shared__ __attribute__((aligned(16))) u16 smem[2 * 128 * 64];   // 32KB
  u16* As = smem;
  u16* Bs = smem + 128 * 64;

  const int tid = threadIdx.x;
  const int w = tid >> 6, lane = tid & 63;
  const int lo = lane & 15, quad = lane >> 4;
  const int which = blockIdx.z;
  const int m0 = blockIdx.x * 128, n0 = blockIdx.y * 128;

  const u16* W = Wb + (size_t)which * (1024 * 1024);
  const int wm = (w >> 1) * 64, wn = (w & 1) * 64;

  floatx4 acc[4][4];
  for (int i = 0; i < 4; ++i)
    for (int j = 0; j < 4; ++j) acc[i][j] = (floatx4)0.f;

  const int arow = lane >> 3;
  const int aswz = ((lane & 7) ^ arow) * 8;

  for (int kt = 0; kt < 16; ++kt) {
    const int k0 = kt * 64;
    for (int j = 0; j < 4; ++j) {
      const int seg = w * 4 + j;
      glds16(As + seg * 512, xb + (size_t)(m0 + seg * 8 + arow) * 1024 + k0 + aswz);
      glds16(Bs + seg * 512, W + (size_t)(n0 + seg * 8 + arow) * 1024 + k0 + aswz);
    }
    __syncthreads();
    for (int kk = 0; kk < 2; ++kk) {
      const int swz = ((kk * 4 + quad) ^ (lo & 7)) * 8;
      bf16x8 af[4], bfr[4];
      for (int it = 0; it < 4; ++it)
        af[it] = *reinterpret_cast<const bf16x8*>(As + (wm + it * 16 + lo) * 64 + swz);
      for (int jt = 0; jt < 4; ++jt)
        bfr[jt] = *reinterpret_cast<const bf16x8*>(Bs + (wn + jt * 16 + lo) * 64 + swz);
      for (int it = 0; it < 4; ++it)
        for (int jt = 0; jt < 4; ++jt)
          acc[it][jt] = MFMA16(af[it], bfr[jt], acc[it][jt]);
    }
    __syncthreads();
  }

  const float* bias = (which == 0) ? bq : (which == 1) ? bk : bv;
  float bb[4];
  for (int jt = 0; jt < 4; ++jt) bb[jt] = bias[n0 + wn + jt * 16 + lo];
  const int b = m0 >> 11;

  if (which < 2) {
    const float scl = (which == 0) ? 0.36067376022224085f : 1.0f;  // 0.25*log2e
    u16* Tw = smem + w * (16 * 72);
    const int hblk = (n0 + wn) >> 6;
    u16* dst = ((which == 0) ? Qb : Kb) +
               ((size_t)(b * 16 + hblk) * 2048 + ((m0 & 2047) + wm)) * 64;
    for (int it = 0; it < 4; ++it) {
      for (int jt = 0; jt < 4; ++jt)
        for (int r = 0; r < 4; ++r) {
          const int m = quad * 4 + r, col = jt * 16 + lo;
          Tw[m * 72 + (((col >> 3) ^ (m & 7)) * 8) + (col & 7)] =
              f2bf((acc[it][jt][r] + bb[jt]) * scl);
        }
      MEMFENCE;
      for (int rd = 0; rd < 2; ++rd) {
        const int sr = rd * 8 + (lane >> 3), d8 = lane & 7;
        bf16x8 v = *reinterpret_cast<const bf16x8*>(Tw + sr * 72 + ((d8 ^ (sr & 7)) * 8));
        *reinterpret_cast<bf16x8*>(dst + (size_t)(it * 16 + sr) * 64 + d8 * 8) = v;
      }
      MEMFENCE;
    }
  } else {
    for (int pass = 0; pass < 2; ++pass) {
      if ((wm >> 6) == pass) {
        for (int it = 0; it < 4; ++it)
          for (int jt = 0; jt < 4; ++jt)
            for (int r = 0; r < 4; ++r) {
              const int n = wn + jt * 16 + lo;
              const int m = it * 16 + quad * 4 + r;
              smem[n * 72 + (((m >> 3) ^ (n & 7)) * 8) + (m & 7)] =
                  f2bf(acc[it][jt][r] + bb[jt]);
            }
      }
      __syncthreads();
      for (int rd = 0; rd < 4; ++rd) {
        const int n = (tid >> 3) + rd * 32, m8 = tid & 7;
        bf16x8 v = *reinterpret_cast<const bf16x8*>(smem + n * 72 + ((m8 ^ (n & 7)) * 8));
        const int ng = n0 + n, h = ng >> 6, d = ng & 63;
        const int s = (m0 & 2047) + pass * 64 + m8 * 8;
        *reinterpret_cast<bf16x8*>(VTb + ((size_t)(b * 16 + h) * 64 + d) * 2048 + s) = v;
      }
      __syncthreads();
    }
  }
}

// ---------------------------------------------------------------- attention
// 1-wave blocks, zero barriers, REGISTER-direct K/V (no LDS staging): plain
// global loads -> compiler-tracked precise vmcnt deps; next tile prefetched
// right after the current QK MFMAs (~500 cyc cover). Fixes R9's starvation:
// 2048 blocks = 8 blocks/CU, matching the 2-waves/SIMD VGPR cap -> 8
// independent waves/CU. One wave = one 32-q tile qt (kstart = qt>>1, n =
// 32-kstart iters; qt ascending = longest-first LPT). LDS only holds the
// 4KB P transpose buffer, with R9's proven same-wave write->read->lgkm(0)->
// rewrite discipline. Fixed-max softmax p=exp2(s'); per-key mask only on
// i==0. Row 2047 -> lrun==0 -> fix2047.
__global__ __launch_bounds__(64, 2) void attn(
    const u16* __restrict__ Qb, const u16* __restrict__ Kb,
    const u16* __restrict__ VTb, float* __restrict__ out) {
  __shared__ __attribute__((aligned(16))) u16 Pt[2][16 * 64];   // 4KB

  const int L = blockIdx.x;        // 2048 blocks
  const int bh = L & 31;           // bh%8 = L%8 -> 4 bh per XCD (L2 locality)
  const int qt = L >> 5;           // 0..63, ascending = longest-first
  const int kstart = qt >> 1;
  const int n = 32 - kstart;

  const int lane = threadIdx.x & 63;
  const int lo = lane & 15, quad = lane >> 4;

  const u16* Qh = Qb + (size_t)bh * (2048 * 64);
  const u16* Kh = Kb + (size_t)bh * (2048 * 64);
  const u16* Vh = VTb + (size_t)bh * (64 * 2048);

  int qrow[2];
  bf16x8 qf[2][2];
  for (int s = 0; s < 2; ++s) {
    qrow[s] = qt * 32 + s * 16 + lo;
    qf[s][0] = *reinterpret_cast<const bf16x8*>(Qh + (size_t)qrow[s] * 64 + quad * 8);
    qf[s][1] = *reinterpret_cast<const bf16x8*>(Qh + (size_t)qrow[s] * 64 + 32 + quad * 8);
  }

  float lrun[2] = {0.f, 0.f};
  floatx4 acc[2][4];
  for (int s = 0; s < 2; ++s)
    for (int dt = 0; dt < 4; ++dt) acc[s][dt] = (floatx4)0.f;

  // K frag (A-op): [kk*4+t] = K[kt*64 + t*16 + lo][kk*32 + quad*8 ..+8]
#define LOADK(D, kt_)                                                         \
  _Pragma("unroll") for (int t = 0; t < 4; ++t) {                             \
    const u16* kp = Kh + (size_t)((kt_) * 64 + t * 16 + lo) * 64 + quad * 8;  \
    D[t] = *reinterpret_cast<const bf16x8*>(kp);                              \
    D[4 + t] = *reinterpret_cast<const bf16x8*>(kp + 32);                     \
  }
  // V frag (A-op): [kk*4+dt] = V^T[dt*16 + lo][kt*64 + kk*32 + quad*8 ..+8]
#define LOADV(D, kt_)                                                         \
  _Pragma("unroll") for (int c = 0; c < 8; ++c) {                             \
    D[c] = *reinterpret_cast<const bf16x8*>(                                  \
        Vh + (size_t)((c & 3) * 16 + lo) * 2048 + (kt_) * 64 +                \
        (c >> 2) * 32 + quad * 8);                                            \
  }

#define ITER(KC, VC, KN, VN)                                                  \
  {                                                                           \
    const int kt = kstart + i;                                                \
    floatx4 sc[2][4];                                                         \
    _Pragma("unroll") for (int s = 0; s < 2; ++s)                             \
      _Pragma("unroll") for (int t = 0; t < 4; ++t) sc[s][t] = (floatx4)0.f;  \
    _Pragma("unroll") for (int kk = 0; kk < 2; ++kk)                          \
      _Pragma("unroll") for (int t = 0; t < 4; ++t) {                         \
        sc[0][t] = MFMA16(KC[kk * 4 + t], qf[0][kk], sc[0][t]);               \
        sc[1][t] = MFMA16(KC[kk * 4 + t], qf[1][kk], sc[1][t]);               \
      }                                                                       \
    if (i + 1 < n) { LOADK(KN, kt + 1); LOADV(VN, kt + 1); }                  \
    const bool maskp = (i == 0);                                              \
    _Pragma("unroll") for (int s = 0; s < 2; ++s) {                           \
      u16* ptw = &Pt[s][0];                                                   \
      _Pragma("unroll") for (int t = 0; t < 4; ++t) {                         \
        float p0 = EXP2(sc[s][t][0]), p1 = EXP2(sc[s][t][1]);                 \
        float p2 = EXP2(sc[s][t][2]), p3 = EXP2(sc[s][t][3]);                 \
        if (maskp) { /* faithful buggy mask: keep key > q */                  \
          const int key = kt * 64 + t * 16 + quad * 4;                        \
          p0 = (key + 0 > qrow[s]) ? p0 : 0.f;                                \
          p1 = (key + 1 > qrow[s]) ? p1 : 0.f;                                \
          p2 = (key + 2 > qrow[s]) ? p2 : 0.f;                                \
          p3 = (key + 3 > qrow[s]) ? p3 : 0.f;                                \
        }                                                                     \
        lrun[s] += (p0 + p1) + (p2 + p3);                                     \
        ushort4 pk;                                                           \
        pk.x = f2bf_hu(p0); pk.y = f2bf_hu(p1);                               \
        pk.z = f2bf_hu(p2); pk.w = f2bf_hu(p3);                               \
        u16* pdst = ptw + lo * 64 +                                           \
                    (((2 * t + (quad >> 1)) ^ (lo & 7)) * 8) + (quad & 1) * 4;\
        *reinterpret_cast<ushort4*>(pdst) = pk;                               \
      }                                                                       \
    }                                                                         \
    MEMFENCE; /* Pt writes ordered before Pt reads (same wave) */             \
    bf16x8 pb[2][2];                                                          \
    _Pragma("unroll") for (int kk = 0; kk < 2; ++kk) {                        \
      const int pswz = ((kk * 4 + quad) ^ (lo & 7)) * 8;                      \
      pb[0][kk] = *reinterpret_cast<const bf16x8*>(&Pt[0][lo * 64] + pswz);   \
      pb[1][kk] = *reinterpret_cast<const bf16x8*>(&Pt[1][lo * 64] + pswz);   \
    }                                                                         \
    WAIT_LGKM0; /* all Pt reads done -> next iter may rewrite */              \
    MEMFENCE;                                                                 \
    _Pragma("unroll") for (int kk = 0; kk < 2; ++kk)                          \
      _Pragma("unroll") for (int dt = 0; dt < 4; ++dt) {                      \
        acc[0][dt] = MFMA16(VC[kk * 4 + dt], pb[0][kk], acc[0][dt]);          \
        acc[1][dt] = MFMA16(VC[kk * 4 + dt], pb[1][kk], acc[1][dt]);          \
      }                                                                       \
    ++i;                                                                      \
  }

  bf16x8 kA[8], vA[8], kB[8], vB[8];
  LOADK(kA, kstart);
  LOADV(vA, kstart);
  int i = 0;
  while (true) {
    ITER(kA, vA, kB, vB);
    if (i >= n) break;
    ITER(kB, vB, kA, vA);
    if (i >= n) break;
  }
#undef ITER
#undef LOADK
#undef LOADV

  const int b = bh >> 4, hh = bh & 15;
  for (int s = 0; s < 2; ++s) {
    float l = lrun[s];
    l += __shfl_xor(l, 16);
    l += __shfl_xor(l, 32);
    if (l != 0.f) {   // l==0 only for fully-masked row 2047 (fix2047)
      const float rl = 1.f / l;
      float* op = out + ((size_t)(b * 2048 + qrow[s])) * 1024 + hh * 64 + quad * 4;
      for (int dt = 0; dt < 4; ++dt) {
        float4 o4;
        o4.x = acc[s][dt][0] * rl; o4.y = acc[s][dt][1] * rl;
        o4.z = acc[s][dt][2] * rl; o4.w = acc[s][dt][3] * rl;
        *reinterpret_cast<float4*>(op + dt * 16) = o4;
      }
    }
  }
}

// ---------------------------------------------------------------- fix2047
// Row 2047 fully masked -> uniform softmax: out = mean_s V[b,s,:].
__global__ __launch_bounds__(256) void fix2047(const u16* __restrict__ VTb,
                                               float* __restrict__ out) {
  const int bh = blockIdx.x;
  const u16* Vh = VTb + (size_t)bh * (64 * 2048);
  const int t = threadIdx.x;
  const int d = t >> 2, j = t & 3;
  float s = 0.f;
  const u16* row = Vh + (size_t)d * 2048 + j * 512;
  for (int i = 0; i < 64; ++i) {
    bf16x8 v = *reinterpret_cast<const bf16x8*>(row + i * 8);
    for (int e = 0; e < 8; ++e) s += bf2f((u16)v[e]);
  }
  s += __shfl_xor(s, 1);
  s += __shfl_xor(s, 2);
  if (j == 0) {
    const int b = bh >> 4, h = bh & 15;
    out[((size_t)(b * 2048 + 2047)) * 1024 + h * 64 + d] = s * (1.f / 2048.f);
  }
}

// ---------------------------------------------------------------- launch
extern "C" void kernel_launch(void* const* d_in, const int* in_sizes, int n_in,
                              void* d_out, int out_size, void* d_ws, size_t ws_size,
                              hipStream_t stream) {
  const float* x  = (const float*)d_in[0];
  const float* Wq = (const float*)d_in[1];
  const float* bq = (const float*)d_in[2];
  const float* Wk = (const float*)d_in[3];
  const float* bk = (const float*)d_in[4];
  const float* Wv = (const float*)d_in[5];
  const float* bv = (const float*)d_in[6];
  float* out = (float*)d_out;

  char* ws = (char*)d_ws;
  u16* xb  = (u16*)(ws);                  // 8 MB: x as bf16 [4096][1024]
  u16* Wb  = (u16*)(ws + (8u << 20));     // 6 MB: Wq,Wk,Wv bf16
  u16* Qb  = (u16*)(ws + (14u << 20));    // 8 MB: Q  [B,H,S,dh] (pre-scaled)
  u16* Kb  = (u16*)(ws + (22u << 20));    // 8 MB: K  [B,H,S,dh]
  u16* VTb = (u16*)(ws + (30u << 20));    // 8 MB: V^T [B,H,dh,S]

  cvt_all<<<7168, 256, 0, stream>>>(x, Wq, Wk, Wv, xb, Wb);
  qkv_gemm<<<dim3(32, 8, 3), 256, 0, stream>>>(xb, Wb, bq, bk, bv, Qb, Kb, VTb);
  attn<<<dim3(2048), 64, 0, stream>>>(Qb, Kb, VTb, out);
  fix2047<<<dim3(32), 256, 0, stream>>>(VTb, out);
}

// Round 11
// 165.496 us; speedup vs baseline: 1.1724x; 1.1724x over previous
//
#include <hip/hip_runtime.h>
#include <stdint.h>

typedef unsigned short u16;
typedef __attribute__((ext_vector_type(8))) short bf16x8;    // 8 bf16 in 4 VGPRs
typedef __attribute__((ext_vector_type(4))) float floatx4;
typedef __attribute__((ext_vector_type(16))) float floatx16;
typedef __attribute__((ext_vector_type(4))) unsigned uintx4;

#define MFMA16(a, b, c) __builtin_amdgcn_mfma_f32_16x16x32_bf16(a, b, c, 0, 0, 0)
#define MFMA32(a, b, c) __builtin_amdgcn_mfma_f32_32x32x16_bf16(a, b, c, 0, 0, 0)
#define MEMFENCE asm volatile("" ::: "memory")

#if __has_builtin(__builtin_amdgcn_exp2f)
#define EXP2(x) __builtin_amdgcn_exp2f(x)
#else
#define EXP2(x) __expf(0.6931471805599453f * (x))
#endif

__device__ __forceinline__ u16 f2bf(float f) {   // round-to-nearest-even
  unsigned u = __builtin_bit_cast(unsigned, f);
  return (u16)((u + 0x7FFFu + ((u >> 16) & 1u)) >> 16);
}
__device__ __forceinline__ unsigned pkbf(float a, float b) {  // round-half-up pack
  unsigned ua = __builtin_bit_cast(unsigned, a);
  unsigned ub = __builtin_bit_cast(unsigned, b);
  return ((ua + 0x8000u) >> 16) | ((ub + 0x8000u) & 0xFFFF0000u);
}
__device__ __forceinline__ float bf2f(u16 v) {
  return __builtin_bit_cast(float, (unsigned)v << 16);
}

// async global->LDS, 16B/lane. LDS dest = wave-uniform base + lane*16 (HW).
__device__ __forceinline__ void glds16(void* lds, const void* g) {
  __builtin_amdgcn_global_load_lds((const __attribute__((address_space(1))) void*)g,
                                   (__attribute__((address_space(3))) void*)lds,
                                   16, 0, 0);
}

// ---------------------------------------------------------------- convert
__global__ __launch_bounds__(256) void cvt_all(
    const float* __restrict__ x, const float* __restrict__ w0,
    const float* __restrict__ w1, const float* __restrict__ w2,
    u16* __restrict__ xb, u16* __restrict__ Wb) {
  const int bid = blockIdx.x;
  const float* src;
  u16* dst;
  int i;
  if (bid < 4096) {
    src = x; dst = xb; i = bid * 256 + threadIdx.x;
  } else {
    const int z = (bid - 4096) >> 10;
    src = (z == 0) ? w0 : (z == 1) ? w1 : w2;
    dst = Wb + (size_t)z * (1024 * 1024);
    i = ((bid - 4096) & 1023) * 256 + threadIdx.x;
  }
  float4 f = reinterpret_cast<const float4*>(src)[i];
  ushort4 o;
  o.x = f2bf(f.x); o.y = f2bf(f.y); o.z = f2bf(f.z); o.w = f2bf(f.w);
  reinterpret_cast<ushort4*>(dst)[i] = o;
}

// ---------------------------------------------------------------- QKV GEMM
// (unchanged from R8 — proven). 128x128 tile, BK=64, 768 blocks = 3/CU,
// XOR-swizzled LDS. which=0 -> Q (pre-scaled 0.25*log2e), 1 -> K, 2 -> V^T.
__global__ __launch_bounds__(256, 3) void qkv_gemm(
    const u16* __restrict__ xb, const u16* __restrict__ Wb,
    const float* __restrict__ bq, const float* __restrict__ bk,
    const float* __restrict__ bv,
    u16* __restrict__ Qb, u16* __restrict__ Kb, u16* __restrict__ VTb) {
  __shared__ __attribute__((aligned(16))) u16 smem[2 * 128 * 64];   // 32KB
  u16* As = smem;
  u16* Bs = smem + 128 * 64;

  const int tid = threadIdx.x;
  const int w = tid >> 6, lane = tid & 63;
  const int lo = lane & 15, quad = lane >> 4;
  const int which = blockIdx.z;
  const int m0 = blockIdx.x * 128, n0 = blockIdx.y * 128;

  const u16* W = Wb + (size_t)which * (1024 * 1024);
  const int wm = (w >> 1) * 64, wn = (w & 1) * 64;

  floatx4 acc[4][4];
  for (int i = 0; i < 4; ++i)
    for (int j = 0; j < 4; ++j) acc[i][j] = (floatx4)0.f;

  const int arow = lane >> 3;
  const int aswz = ((lane & 7) ^ arow) * 8;

  for (int kt = 0; kt < 16; ++kt) {
    const int k0 = kt * 64;
    for (int j = 0; j < 4; ++j) {
      const int seg = w * 4 + j;
      glds16(As + seg * 512, xb + (size_t)(m0 + seg * 8 + arow) * 1024 + k0 + aswz);
      glds16(Bs + seg * 512, W + (size_t)(n0 + seg * 8 + arow) * 1024 + k0 + aswz);
    }
    __syncthreads();
    for (int kk = 0; kk < 2; ++kk) {
      const int swz = ((kk * 4 + quad) ^ (lo & 7)) * 8;
      bf16x8 af[4], bfr[4];
      for (int it = 0; it < 4; ++it)
        af[it] = *reinterpret_cast<const bf16x8*>(As + (wm + it * 16 + lo) * 64 + swz);
      for (int jt = 0; jt < 4; ++jt)
        bfr[jt] = *reinterpret_cast<const bf16x8*>(Bs + (wn + jt * 16 + lo) * 64 + swz);
      for (int it = 0; it < 4; ++it)
        for (int jt = 0; jt < 4; ++jt)
          acc[it][jt] = MFMA16(af[it], bfr[jt], acc[it][jt]);
    }
    __syncthreads();
  }

  const float* bias = (which == 0) ? bq : (which == 1) ? bk : bv;
  float bb[4];
  for (int jt = 0; jt < 4; ++jt) bb[jt] = bias[n0 + wn + jt * 16 + lo];
  const int b = m0 >> 11;

  if (which < 2) {
    const float scl = (which == 0) ? 0.36067376022224085f : 1.0f;  // 0.25*log2e
    u16* Tw = smem + w * (16 * 72);
    const int hblk = (n0 + wn) >> 6;
    u16* dst = ((which == 0) ? Qb : Kb) +
               ((size_t)(b * 16 + hblk) * 2048 + ((m0 & 2047) + wm)) * 64;
    for (int it = 0; it < 4; ++it) {
      for (int jt = 0; jt < 4; ++jt)
        for (int r = 0; r < 4; ++r) {
          const int m = quad * 4 + r, col = jt * 16 + lo;
          Tw[m * 72 + (((col >> 3) ^ (m & 7)) * 8) + (col & 7)] =
              f2bf((acc[it][jt][r] + bb[jt]) * scl);
        }
      MEMFENCE;
      for (int rd = 0; rd < 2; ++rd) {
        const int sr = rd * 8 + (lane >> 3), d8 = lane & 7;
        bf16x8 v = *reinterpret_cast<const bf16x8*>(Tw + sr * 72 + ((d8 ^ (sr & 7)) * 8));
        *reinterpret_cast<bf16x8*>(dst + (size_t)(it * 16 + sr) * 64 + d8 * 8) = v;
      }
      MEMFENCE;
    }
  } else {
    for (int pass = 0; pass < 2; ++pass) {
      if ((wm >> 6) == pass) {
        for (int it = 0; it < 4; ++it)
          for (int jt = 0; jt < 4; ++jt)
            for (int r = 0; r < 4; ++r) {
              const int n = wn + jt * 16 + lo;
              const int m = it * 16 + quad * 4 + r;
              smem[n * 72 + (((m >> 3) ^ (n & 7)) * 8) + (m & 7)] =
                  f2bf(acc[it][jt][r] + bb[jt]);
            }
      }
      __syncthreads();
      for (int rd = 0; rd < 4; ++rd) {
        const int n = (tid >> 3) + rd * 32, m8 = tid & 7;
        bf16x8 v = *reinterpret_cast<const bf16x8*>(smem + n * 72 + ((m8 ^ (n & 7)) * 8));
        const int ng = n0 + n, h = ng >> 6, d = ng & 63;
        const int s = (m0 & 2047) + pass * 64 + m8 * 8;
        *reinterpret_cast<bf16x8*>(VTb + ((size_t)(b * 16 + h) * 64 + d) * 2048 + s) = v;
      }
      __syncthreads();
    }
  }
}

// ---------------------------------------------------------------- attention
// 32x32x16-MFMA transposed flash. Wave = 32 q (one n-group), block = 2 waves
// = 64-q tile -> 1024 blocks (32 bh x 32 qt), 4-5 blocks/CU co-resident
// (LDS = 32KB: K/V dbuf only). The P transform (S^T C-layout -> PV B-operand)
// stays in registers: both have q = lane&31; only the lane h-halves (^32)
// exchange, via 8 shfl_xor + cndmasks -- no Pt LDS round trip, no fences.
// Fixed-max softmax p = exp2(s') (shift-invariant, bounded); mask only on the
// diagonal (first) k-tile. qt = L>>5 ascending = longest-first (LPT).
// Row 2047 -> lrun==0 -> fix2047.
__global__ __launch_bounds__(128, 2) void attn(
    const u16* __restrict__ Qb, const u16* __restrict__ Kb,
    const u16* __restrict__ VTb, float* __restrict__ out) {
  __shared__ __attribute__((aligned(16))) u16 Ks[2][64 * 64];   // [key][d] swz
  __shared__ __attribute__((aligned(16))) u16 Vs[2][64 * 64];   // [d][key] swz

  const int L = blockIdx.x;        // 1024 blocks
  const int bh = L & 31;           // bh%8 = L%8 -> 4 bh per XCD (L2 locality)
  const int qt = L >> 5;           // 0..31 ascending = longest first
  const int kstart = qt, n = 32 - qt;

  const int tid = threadIdx.x;     // 128 threads, 2 waves
  const int wq = tid >> 6, lane = tid & 63;
  const int l31 = lane & 31, h = lane >> 5;

  const u16* Qh = Qb + (size_t)bh * (2048 * 64);
  const u16* Kh = Kb + (size_t)bh * (2048 * 64);
  const u16* Vh = VTb + (size_t)bh * (64 * 2048);

  // Q frags (B-op of 32x32x16): B[k = kk*16 + h*8 + j][n = q = l31]
  const int qrow = qt * 64 + wq * 32 + l31;
  bf16x8 qf[4];
  for (int kk = 0; kk < 4; ++kk)
    qf[kk] = *reinterpret_cast<const bf16x8*>(Qh + (size_t)qrow * 64 + kk * 16 + h * 8);

  float lrun = 0.f;
  floatx16 acc[2];
  acc[0] = (floatx16)0.f;
  acc[1] = (floatx16)0.f;

  const int srow8 = lane >> 3, sblk = lane & 7;
  const int sswz = (sblk ^ srow8) * 8;          // staging XOR swizzle

  // stage 64-key tile kt into buffer buf; 2 waves cover 8+8 segs
#define STAGE(buf, kt_)                                                       \
  for (int j = 0; j < 4; ++j) {                                               \
    const int r0 = wq * 32 + j * 8;                                           \
    glds16(&Ks[buf][r0 * 64], Kh + (size_t)((kt_) * 64 + r0 + srow8) * 64 + sswz); \
    glds16(&Vs[buf][r0 * 64], Vh + (size_t)(r0 + srow8) * 2048 + (kt_) * 64 + sswz); \
  }

  STAGE(0, kstart);
  __syncthreads();

  for (int kt = kstart; kt < 32; ++kt) {
    const int cur = (kt - kstart) & 1, nxt = cur ^ 1;
    if (kt < 31) { STAGE(nxt, kt + 1); }     // prefetch before compute
    const u16* ksb = Ks[cur];
    const u16* vsb = Vs[cur];

    // S^T = K*Q^T : A = K[key = m*32+l31][d = kk*16 + h*8 + j]
    floatx16 sc[2];
    sc[0] = (floatx16)0.f;
    sc[1] = (floatx16)0.f;
    for (int kk = 0; kk < 4; ++kk) {
      const int ch = kk * 2 + h;             // 16B chunk within 64-d row
      for (int m = 0; m < 2; ++m) {
        const int row = m * 32 + l31;
        bf16x8 ka = *reinterpret_cast<const bf16x8*>(
            ksb + row * 64 + ((ch ^ (row & 7)) * 8));
        sc[m] = MFMA32(ka, qf[kk], sc[m]);
      }
    }

    // p = exp2(s'); C-layout: col = q = l31 (own!), row key = (r&3)+8g+4h+m*32
    const bool maskp = (kt == kstart);
    unsigned pw[2][8];
#pragma unroll
    for (int m = 0; m < 2; ++m)
#pragma unroll
      for (int g = 0; g < 4; ++g) {
        float p0 = EXP2(sc[m][4 * g + 0]), p1 = EXP2(sc[m][4 * g + 1]);
        float p2 = EXP2(sc[m][4 * g + 2]), p3 = EXP2(sc[m][4 * g + 3]);
        if (maskp) {   // faithful buggy mask: keep key > q
          const int keyb = kt * 64 + m * 32 + 8 * g + 4 * h;
          p0 = (keyb + 0 > qrow) ? p0 : 0.f;
          p1 = (keyb + 1 > qrow) ? p1 : 0.f;
          p2 = (keyb + 2 > qrow) ? p2 : 0.f;
          p3 = (keyb + 3 > qrow) ? p3 : 0.f;
        }
        lrun += (p0 + p1) + (p2 + p3);
        pw[m][2 * g] = pkbf(p0, p1);
        pw[m][2 * g + 1] = pkbf(p2, p3);
      }

    // h-partner exchange: each lane sends the half its partner needs
    unsigned y[2][4];
#pragma unroll
    for (int m = 0; m < 2; ++m)
#pragma unroll
      for (int lh = 0; lh < 2; ++lh)
#pragma unroll
        for (int j = 0; j < 2; ++j) {
          const unsigned s = h ? pw[m][4 * lh + j] : pw[m][4 * lh + 2 + j];
          y[m][2 * lh + j] = __shfl_xor(s, 32);
        }

    // assemble PV B-frags: B[k = c*16 + h*8 + j][n = q = l31]
    bf16x8 pb[4];
#pragma unroll
    for (int c = 0; c < 4; ++c) {
      const int m = c >> 1, lh = c & 1;
      uintx4 u;
      u.x = h ? y[m][2 * lh]      : pw[m][4 * lh];
      u.y = h ? y[m][2 * lh + 1]  : pw[m][4 * lh + 1];
      u.z = h ? pw[m][4 * lh + 2] : y[m][2 * lh];
      u.w = h ? pw[m][4 * lh + 3] : y[m][2 * lh + 1];
      pb[c] = __builtin_bit_cast(bf16x8, u);
    }

    // O^T += V^T * P^T : A = V^T[d = dt*32+l31][key = c*16 + h*8 + j]
    for (int c = 0; c < 4; ++c) {
      const int ch = c * 2 + h;
      for (int dt = 0; dt < 2; ++dt) {
        const int row = dt * 32 + l31;
        bf16x8 va = *reinterpret_cast<const bf16x8*>(
            vsb + row * 64 + ((ch ^ (row & 7)) * 8));
        acc[dt] = MFMA32(va, pb[c], acc[dt]);
      }
    }
    __syncthreads();   // staging of nxt complete + both waves done with cur
  }
#undef STAGE

  lrun += __shfl_xor(lrun, 32);
  if (lrun != 0.f) {   // lrun==0 only for fully-masked row 2047 (fix2047)
    const float rl = 1.f / lrun;
    const int b = bh >> 4, hh = bh & 15;
    float* op = out + ((size_t)(b * 2048 + qrow)) * 1024 + hh * 64;
    for (int dt = 0; dt < 2; ++dt)
      for (int g = 0; g < 4; ++g) {
        float4 o4;   // rows d = dt*32 + 8g + 4h + (0..3)
        o4.x = acc[dt][4 * g + 0] * rl;
        o4.y = acc[dt][4 * g + 1] * rl;
        o4.z = acc[dt][4 * g + 2] * rl;
        o4.w = acc[dt][4 * g + 3] * rl;
        *reinterpret_cast<float4*>(op + dt * 32 + 8 * g + 4 * h) = o4;
      }
  }
}

// ---------------------------------------------------------------- fix2047
// Row 2047 fully masked -> uniform softmax: out = mean_s V[b,s,:].
__global__ __launch_bounds__(256) void fix2047(const u16* __restrict__ VTb,
                                               float* __restrict__ out) {
  const int bh = blockIdx.x;
  const u16* Vh = VTb + (size_t)bh * (64 * 2048);
  const int t = threadIdx.x;
  const int d = t >> 2, j = t & 3;
  float s = 0.f;
  const u16* row = Vh + (size_t)d * 2048 + j * 512;
  for (int i = 0; i < 64; ++i) {
    bf16x8 v = *reinterpret_cast<const bf16x8*>(row + i * 8);
    for (int e = 0; e < 8; ++e) s += bf2f((u16)v[e]);
  }
  s += __shfl_xor(s, 1);
  s += __shfl_xor(s, 2);
  if (j == 0) {
    const int b = bh >> 4, h = bh & 15;
    out[((size_t)(b * 2048 + 2047)) * 1024 + h * 64 + d] = s * (1.f / 2048.f);
  }
}

// ---------------------------------------------------------------- launch
extern "C" void kernel_launch(void* const* d_in, const int* in_sizes, int n_in,
                              void* d_out, int out_size, void* d_ws, size_t ws_size,
                              hipStream_t stream) {
  const float* x  = (const float*)d_in[0];
  const float* Wq = (const float*)d_in[1];
  const float* bq = (const float*)d_in[2];
  const float* Wk = (const float*)d_in[3];
  const float* bk = (const float*)d_in[4];
  const float* Wv = (const float*)d_in[5];
  const float* bv = (const float*)d_in[6];
  float* out = (float*)d_out;

  char* ws = (char*)d_ws;
  u16* xb  = (u16*)(ws);                  // 8 MB: x as bf16 [4096][1024]
  u16* Wb  = (u16*)(ws + (8u << 20));     // 6 MB: Wq,Wk,Wv bf16
  u16* Qb  = (u16*)(ws + (14u << 20));    // 8 MB: Q  [B,H,S,dh] (pre-scaled)
  u16* Kb  = (u16*)(ws + (22u << 20));    // 8 MB: K  [B,H,S,dh]
  u16* VTb = (u16*)(ws + (30u << 20));    // 8 MB: V^T [B,H,dh,S]

  cvt_all<<<7168, 256, 0, stream>>>(x, Wq, Wk, Wv, xb, Wb);
  qkv_gemm<<<dim3(32, 8, 3), 256, 0, stream>>>(xb, Wb, bq, bk, bv, Qb, Kb, VTb);
  attn<<<dim3(1024), 128, 0, stream>>>(Qb, Kb, VTb, out);
  fix2047<<<dim3(32), 256, 0, stream>>>(VTb, out);
}